// Round 5
// baseline (504.000 us; speedup 1.0000x reference)
//
#include <hip/hip_runtime.h>

typedef _Float16 f16x8 __attribute__((ext_vector_type(8)));
typedef _Float16 f16x2 __attribute__((ext_vector_type(2)));
typedef float f32x4 __attribute__((ext_vector_type(4)));

#define SLOT_DW 2048              // dwords per (b,t) slot: kA writes 1408 dw (f16 band), kB overwrites with 2048 dw frame
#define WT_BYTE_OFF 134217728     // 16384*2048*4 ; Wt (f16) after slots
#define PHYS(i) ((i) + ((i) >> 5))   // LDS pad swizzle for FFT buffers

__device__ __forceinline__ void async_copy16(const void* g, void* l) {
  __builtin_amdgcn_global_load_lds((const __attribute__((address_space(1))) void*)g,
                                   (__attribute__((address_space(3))) void*)l, 16, 0, 0);
}

// ---------------- K0: transpose+scale W -> Wt[n][o][d] (f16, x4096) ----------------
__global__ __launch_bounds__(256) void k_init(const float* __restrict__ W,
                                              _Float16* __restrict__ Wt) {
  int n = blockIdx.x >> 2, dq = blockIdx.x & 3;
  int tid = threadIdx.x;
  __shared__ _Float16 L[32 * 130];
  const float* Wn = W + (size_t)n * 16384 + dq * 32 * 128;
  for (int el = tid; el < 4096; el += 256) {
    int dl = el >> 7, o = el & 127;
    L[dl * 130 + o] = (_Float16)(Wn[el] * 4096.0f);
  }
  __syncthreads();
  _Float16* Wtn = Wt + (size_t)n * 16384 + dq * 32;
  for (int el = tid; el < 4096; el += 256) {
    int o = el >> 5, dl = el & 31;
    Wtn[o * 128 + dl] = L[dl * 130 + o];
  }
}

// ---------------- KA: streaming GEMM — one block = 16 rows x ALL 22 bands, dbuf async staging ----------------
// Per band: wave w owns col-tiles {2w, 2w+1}; M=16 (one row-tile). z staged fp32 via global_load_lds.
__global__ __launch_bounds__(256) void kA(const float* __restrict__ z,
                                          const _Float16* __restrict__ Wt,
                                          _Float16* __restrict__ band) {
  int r0 = blockIdx.x * 16;     // grid 1024
  __shared__ __align__(16) char bufZ[2][8 * 1040];   // 8 row-pairs x (1024B data + 16B pad)
  __shared__ __align__(16) _Float16 Cs[16 * 136];
  int tid = threadIdx.x;
  int lane = tid & 63, wave = tid >> 6;
  int l16 = lane & 15, quad = lane >> 4;
  int col16 = lane & 31, rowh = lane >> 5;

  // stage band n's 16 z-rows into bufZ[s]: 8 DMA instrs (2/wave), 1 KB each (2 rows)
  int pr0 = wave * 2;
  {
    const float* g0 = z + ((size_t)(r0 + 2 * pr0 + rowh) * 22 + 0) * 128 + col16 * 4;
    const float* g1 = z + ((size_t)(r0 + 2 * pr0 + 2 + rowh) * 22 + 0) * 128 + col16 * 4;
    async_copy16(g0, &bufZ[0][pr0 * 1040]);
    async_copy16(g1, &bufZ[0][(pr0 + 1) * 1040]);
  }

  for (int n = 0; n < 22; n++) {
    __syncthreads();            // drains DMA for band n; protects Cs + other buf
    int cur = n & 1;
    const _Float16* Wn = Wt + (size_t)n * 16384;
    f16x8 b0[4], b1[4];
#pragma unroll
    for (int kb = 0; kb < 4; kb++) {
      int ko = kb * 32 + quad * 8;
      b0[kb] = *(const f16x8*)(Wn + (wave * 32 + l16) * 128 + ko);
      b1[kb] = *(const f16x8*)(Wn + (wave * 32 + 16 + l16) * 128 + ko);
    }
    f32x4 a0 = (f32x4){0.f, 0.f, 0.f, 0.f};
    f32x4 a1 = (f32x4){0.f, 0.f, 0.f, 0.f};
    const float* bz = (const float*)&bufZ[cur][0];
    int abase = (l16 >> 1) * 260 + (l16 & 1) * 128 + quad * 8;
#pragma unroll
    for (int kb = 0; kb < 4; kb++) {
      const float* ap = bz + abase + kb * 32;
      float4 v0 = *(const float4*)ap;
      float4 v1 = *(const float4*)(ap + 4);
      f16x8 a;
      a[0] = (_Float16)v0.x; a[1] = (_Float16)v0.y; a[2] = (_Float16)v0.z; a[3] = (_Float16)v0.w;
      a[4] = (_Float16)v1.x; a[5] = (_Float16)v1.y; a[6] = (_Float16)v1.z; a[7] = (_Float16)v1.w;
      a0 = __builtin_amdgcn_mfma_f32_16x16x32_f16(a, b0[kb], a0, 0, 0, 0);
      a1 = __builtin_amdgcn_mfma_f32_16x16x32_f16(a, b1[kb], a1, 0, 0, 0);
    }
    const float inv_scale = 1.0f / 4096.0f;
#pragma unroll
    for (int reg = 0; reg < 4; reg++) {
      int row = quad * 4 + reg;
      Cs[row * 136 + (wave * 2) * 16 + l16]     = (_Float16)(a0[reg] * inv_scale);
      Cs[row * 136 + (wave * 2 + 1) * 16 + l16] = (_Float16)(a1[reg] * inv_scale);
    }
    __syncthreads();            // Cs visible
    // coalesced store: 16 threads/row x 16B
    {
      int row = tid >> 4, c8 = (tid & 15) * 8;
      f16x8 v = *(const f16x8*)&Cs[row * 136 + c8];
      *(f16x8*)(band + (size_t)(r0 + row) * (SLOT_DW * 2) + n * 128 + c8) = v;
    }
    // prefetch band n+1 (issued after last barrier -> drained exactly at next iter's top barrier)
    if (n + 1 < 22) {
      const float* g0 = z + ((size_t)(r0 + 2 * pr0 + rowh) * 22 + (n + 1)) * 128 + col16 * 4;
      const float* g1 = z + ((size_t)(r0 + 2 * pr0 + 2 + rowh) * 22 + (n + 1)) * 128 + col16 * 4;
      async_copy16(g0, &bufZ[cur ^ 1][pr0 * 1040]);
      async_copy16(g1, &bufZ[cur ^ 1][(pr0 + 1) * 1040]);
    }
  }
}

// ---------------- KB: mask gather + pack (conjugate pairs) + radix-4 Stockham IFFT + window ----------------
__global__ __launch_bounds__(256) void kB(const float* __restrict__ mix,
                                          const float* __restrict__ bias,
                                          float* __restrict__ ws) {
  int r = blockIdx.x;           // 0..16383
  int b = r >> 11, t = r & 2047;
  __shared__ __align__(16) float2 bufA[1056];   // swizzled: PHYS(i)=i+(i>>5)
  __shared__ __align__(16) float2 bufB[1056];
  int tid = threadIdx.x;

  const _Float16* bandg = (const _Float16*)(ws + (size_t)r * SLOT_DW);
  const float2* bias2 = (const float2*)bias;
  const float* mixr = mix + ((size_t)(b * 2) * 2048 + t) * 1025;
  const float* mixi = mix + ((size_t)(b * 2 + 1) * 2048 + t) * 1025;

  // ---- fused mask gather + complex-mul + real-pack (pairs k, 1024-k) ----
  for (int k = tid; k <= 512; k += 256) {
    float2 X[2];
#pragma unroll
    for (int side = 0; side < 2; side++) {
      int f = side ? (1024 - k) : k;
      float mr = 0.f, mi = 0.f;
      int wgt = 0;
      int nhi = f / 48; if (nhi > 20) nhi = 20;
      int nlo = (f >= 16) ? (f - 16) / 48 : 0;
      for (int n = nlo; n <= nhi; n++) {
        int idx = n * 128 + 2 * (f - n * 48);
        f16x2 bv = *(const f16x2*)(bandg + idx);
        float2 bb = bias2[idx >> 1];
        mr += (float)bv[0] + bb.x;
        mi += (float)bv[1] + bb.y;
        wgt++;
      }
      if (f >= 961) {
        int idx = 21 * 128 + 2 * (f - 961);
        f16x2 bv = *(const f16x2*)(bandg + idx);
        float2 bb = bias2[idx >> 1];
        mr += (float)bv[0] + bb.x;
        mi += (float)bv[1] + bb.y;
        wgt++;
      }
      float inv = (wgt == 1) ? 1.0f : ((wgt == 2) ? 0.5f : (1.0f / 3.0f));
      mr *= inv; mi *= inv;
      float xr = mixr[f], xi = mixi[f];
      float outr = mr * xr - mi * xi;
      float outi = mr * xi + mi * xr;
      if (f == 0 || f == 1024) outi = 0.0f;   // c2r ignores Im at DC/Nyquist
      X[side] = make_float2(outr, outi);
      if (k == 512) { X[1] = X[0]; break; }   // self-paired center
    }
    float Ar = X[0].x + X[1].x, Ai = X[0].y - X[1].y;
    float Br = X[0].x - X[1].x, Bi = X[0].y + X[1].y;
    float sv, cv;
    __sincosf((float)k * 3.0679615757712823e-3f, &sv, &cv);   // pi/1024
    float s1 = cv * Bi + sv * Br;
    float s2 = cv * Br - sv * Bi;
    bufA[PHYS(k & 1023)] = make_float2(Ar - s1, Ai + s2);
    if (k > 0 && k < 512) bufA[PHYS(1024 - k)] = make_float2(Ar + s1, -Ai + s2);
  }

  // ---- radix-4 Stockham inverse FFT (5 double-stages, e^{+i} twiddles, unnormalized) ----
  float2* src = bufA;
  float2* dst = bufB;
#pragma unroll
  for (int st = 0; st < 5; st++) {
    const int s = 2 * st;
    const int m = 1 << s;
    __syncthreads();
    int q = tid >> s, rr = tid & (m - 1);
    float2 x0 = src[PHYS(tid)];
    float2 x1 = src[PHYS(tid + 256)];
    float2 x2 = src[PHYS(tid + 512)];
    float2 x3 = src[PHYS(tid + 768)];
    float ang = (float)(q * m) * 6.135923151542565e-3f;   // 2*pi*q*m/1024
    float ws1, wc1;
    __sincosf(ang, &ws1, &wc1);
    float wc2 = wc1 * wc1 - ws1 * ws1, ws2 = 2.0f * wc1 * ws1;
    float wc3 = wc2 * wc1 - ws2 * ws1, ws3 = wc2 * ws1 + ws2 * wc1;
    float tAr = x0.x + x2.x, tAi = x0.y + x2.y;
    float tBr = x0.x - x2.x, tBi = x0.y - x2.y;
    float tCr = x1.x + x3.x, tCi = x1.y + x3.y;
    float tDr = x1.x - x3.x, tDi = x1.y - x3.y;
    int base = 4 * q * m + rr;
    dst[PHYS(base)] = make_float2(tAr + tCr, tAi + tCi);
    float pr = tBr - tDi, pi = tBi + tDr;                  // tB + i*tD
    dst[PHYS(base + m)] = make_float2(wc1 * pr - ws1 * pi, wc1 * pi + ws1 * pr);
    float qr = tAr - tCr, qi = tAi - tCi;
    dst[PHYS(base + 2 * m)] = make_float2(wc2 * qr - ws2 * qi, wc2 * qi + ws2 * qr);
    float rr2 = tBr + tDi, ri2 = tBi - tDr;                // tB - i*tD
    dst[PHYS(base + 3 * m)] = make_float2(wc3 * rr2 - ws3 * ri2, wc3 * ri2 + ws3 * rr2);
    float2* tmp = src; src = dst; dst = tmp;
  }
  __syncthreads();

  // ---- window + store frame (x[2j]=Re(g[j])/2048, x[2j+1]=Im(g[j])/2048) ----
  float2* slot2 = (float2*)(ws + (size_t)r * SLOT_DW);
  const float inv_n = 1.0f / 2048.0f;
  for (int j = tid; j < 1024; j += 256) {
    float2 g = src[PHYS(j)];
    float c0 = __cosf((float)(2 * j) * 3.0679615757712823e-3f);
    float c1 = __cosf((float)(2 * j + 1) * 3.0679615757712823e-3f);
    float w0 = 0.5f * (1.0f - c0);
    float w1 = 0.5f * (1.0f - c1);
    slot2[j] = make_float2(g.x * inv_n * w0, g.y * inv_n * w1);
  }
}

// ---------------- KC: overlap-add gather, 4 outputs/thread, float4 fast path ----------------
__global__ __launch_bounds__(256) void kC(const float* __restrict__ ws,
                                          float* __restrict__ out) {
  int b = blockIdx.y;
  int p0 = (blockIdx.x * 256 + threadIdx.x) * 4;
  if (p0 >= 1048064) return;
  int q0 = p0 + 1024;
  int tA = (q0 >= 1536) ? ((q0 - 1536) >> 9) : 0;
  int tB = (q0 + 3) >> 9; if (tB > 2047) tB = 2047;
  const float* base = ws + (size_t)b * 2048 * SLOT_DW;
  float s0 = 0.f, s1 = 0.f, s2 = 0.f, s3 = 0.f;
  if ((q0 & 511) <= 508) {
    // all contributing float4 loads are fully in-slot and 16B-aligned
    for (int t = tA; t <= tB; t++) {
      int i0 = q0 - (t << 9);
      float4 v = *(const float4*)(base + (size_t)t * SLOT_DW + i0);
      s0 += v.x; s1 += v.y; s2 += v.z; s3 += v.w;
    }
  } else {
    for (int t = tA; t <= tB; t++) {
      int i0 = q0 - (t << 9);
      const float* fp = base + (size_t)t * SLOT_DW;
#pragma unroll
      for (int j = 0; j < 4; j++) {
        int i = i0 + j;
        float v = (i >= 0 && i < 2048) ? fp[i] : 0.f;
        float* sp = (j == 0) ? &s0 : (j == 1) ? &s1 : (j == 2) ? &s2 : &s3;
        *sp += v;
      }
    }
  }
  float4 r;
  float* sv[4] = {&s0, &s1, &s2, &s3};
  float rv[4];
#pragma unroll
  for (int j = 0; j < 4; j++) {
    int q = q0 + j;
    float env;
    if (q >= 1536 && q <= 1048575) {
      env = 1.5f;   // Hann, hop=WIN/4: interior sum of win^2 is exactly 1.5
    } else {
      env = 0.f;
      int t0e = (q >= 1536) ? ((q - 1536) >> 9) : 0;
      int t1e = q >> 9; if (t1e > 2047) t1e = 2047;
      for (int t = t0e; t <= t1e; t++) {
        int i = q - (t << 9);
        float c = __cosf((float)i * 3.0679615757712823e-3f);
        float win = 0.5f * (1.0f - c);
        env += win * win;
      }
      if (env <= 1e-11f) env = 1.0f;
    }
    rv[j] = *sv[j] / env;
  }
  r.x = rv[0]; r.y = rv[1]; r.z = rv[2]; r.w = rv[3];
  *(float4*)(out + (size_t)b * 1048064 + p0) = r;
}

extern "C" void kernel_launch(void* const* d_in, const int* in_sizes, int n_in,
                              void* d_out, int out_size, void* d_ws, size_t ws_size,
                              hipStream_t stream) {
  const float* z    = (const float*)d_in[0];
  const float* mix  = (const float*)d_in[1];
  const float* W    = (const float*)d_in[2];
  const float* bias = (const float*)d_in[3];
  float* out = (float*)d_out;
  _Float16* Wt = (_Float16*)((char*)d_ws + WT_BYTE_OFF);

  k_init<<<88, 256, 0, stream>>>(W, Wt);
  kA<<<1024, 256, 0, stream>>>(z, Wt, (_Float16*)d_ws);
  kB<<<16384, 256, 0, stream>>>(mix, bias, (float*)d_ws);
  kC<<<dim3(1024, 8), 256, 0, stream>>>((const float*)d_ws, out);
}